// Round 1
// baseline (400.922 us; speedup 1.0000x reference)
//
#include <hip/hip_runtime.h>
#include <stdint.h>

typedef unsigned short u16;
typedef __attribute__((ext_vector_type(8))) short short8v;
typedef __attribute__((ext_vector_type(4))) float f32x4;

#define B_ 8
#define T_ 8192
#define H_ 256
#define M_ 65536            // B_*T_
#define MH 16777216         // M_*H_
#define NCH 64              // chunks along T
#define CHL 128             // T_/NCH
#define NCHAN 4096          // 2*B_*H_

__device__ __forceinline__ u16 f2bf(float f) {
  union { float f; uint32_t u; } v; v.f = f;
  return (u16)((v.u + 0x7FFFu + ((v.u >> 16) & 1u)) >> 16);
}
__device__ __forceinline__ float bf2f(u16 s) {
  union { uint32_t u; float f; } v; v.u = ((uint32_t)s) << 16;
  return v.f;
}
__device__ __forceinline__ float sigm(float x) {
  return __fdividef(1.0f, 1.0f + __expf(-x));
}
__device__ __forceinline__ float tanhfast(float x) {
  // 1 - 2/(e^{2x}+1); saturates correctly for |x| large
  return 1.0f - __fdividef(2.0f, __expf(2.0f * x) + 1.0f);
}

// ---------------- converts ----------------
__global__ __launch_bounds__(256) void cvt_x_kernel(const float* __restrict__ x,
                                                    u16* __restrict__ xf) {
  size_t i = ((size_t)blockIdx.x * 256 + threadIdx.x) * 8;
  const float4* src = (const float4*)(x + i);
  float4 a = src[0], b = src[1];
  short8v o;
  o[0] = (short)f2bf(a.x); o[1] = (short)f2bf(a.y);
  o[2] = (short)f2bf(a.z); o[3] = (short)f2bf(a.w);
  o[4] = (short)f2bf(b.x); o[5] = (short)f2bf(b.y);
  o[6] = (short)f2bf(b.z); o[7] = (short)f2bf(b.w);
  *(short8v*)(xf + i) = o;
}

__global__ __launch_bounds__(256) void cvt_w_kernel(const float* __restrict__ s0, const float* __restrict__ s1,
                                                    const float* __restrict__ s2, const float* __restrict__ s3,
                                                    const float* __restrict__ s4, const float* __restrict__ s5,
                                                    u16* __restrict__ wbf) {
  int i = blockIdx.x * 256 + threadIdx.x;       // < 6*65536
  int m = i >> 16, r = i & 65535;
  const float* s = (m == 0) ? s0 : (m == 1) ? s1 : (m == 2) ? s2 : (m == 3) ? s3 : (m == 4) ? s4 : s5;
  wbf[i] = f2bf(s[r]);
}

// ---------------- GEMM: C[m,n] = epi(sum_k A[m,k]*Bw[n,k] + bias[n]) ----------------
// A: M x 256 bf16 row-major; Bw: 256 x 256 bf16 row-major (N,K); C: M x 256 bf16.
// EPI: 0 = tanh(+bias), 1 = +bias, 2 = none.  REV: reverse A rows per batch (time flip).
__device__ __forceinline__ void g2l16(const void* g, void* l) {
  __builtin_amdgcn_global_load_lds((const __attribute__((address_space(1))) void*)g,
                                   (__attribute__((address_space(3))) void*)l, 16, 0, 0);
}

template <int EPI, int REV>
__global__ __launch_bounds__(256) void gemm_k(const u16* __restrict__ A,
                                              const u16* __restrict__ Bw,
                                              const float* __restrict__ bias,
                                              u16* __restrict__ C) {
  __shared__ __align__(16) char ldsA[16384];    // 128 rows x 64 bf16 (128B/row)
  __shared__ __align__(16) char ldsB[16384];
  const int tid = threadIdx.x;
  const int l = tid & 63, w = tid >> 6;
  const int tm = blockIdx.x, tn = blockIdx.y;
  const int m0 = (w >> 1) * 64, n0 = (w & 1) * 64;
  const int wbase = w * 1024;

  f32x4 vzero = {0.f, 0.f, 0.f, 0.f};
  f32x4 acc[4][4];
#pragma unroll
  for (int i = 0; i < 4; ++i)
#pragma unroll
    for (int j = 0; j < 4; ++j) acc[i][j] = vzero;

#pragma unroll
  for (int k0 = 0; k0 < 256; k0 += 64) {
#pragma unroll
    for (int is = 0; is < 4; ++is) {
      const int o = is * 4096 + tid * 16;
      const int row = o >> 7;                   // 0..127
      const int cb = o & 127;                   // byte within 128B row
      int rA = tm * 128 + row;
      if (REV) { int bb = rA >> 13; int t = rA & 8191; rA = (bb << 13) + (8191 - t); }
      const char* gA = (const char*)A + (size_t)rA * 512 + k0 * 2 + cb;
      g2l16(gA, ldsA + is * 4096 + wbase);
      const int rB = tn * 128 + row;
      const char* gB = (const char*)Bw + (size_t)rB * 512 + k0 * 2 + cb;
      g2l16(gB, ldsB + is * 4096 + wbase);
    }
    __syncthreads();                            // drains vmcnt (global_load_lds) + barrier
#pragma unroll
    for (int ks = 0; ks < 2; ++ks) {
      short8v av[4], bv[4];
#pragma unroll
      for (int i = 0; i < 4; ++i) {
        av[i] = *(const short8v*)(ldsA + (m0 + i * 16 + (l & 15)) * 128 + ks * 64 + (l >> 4) * 16);
        bv[i] = *(const short8v*)(ldsB + (n0 + i * 16 + (l & 15)) * 128 + ks * 64 + (l >> 4) * 16);
      }
#pragma unroll
      for (int i = 0; i < 4; ++i)
#pragma unroll
        for (int j = 0; j < 4; ++j)
          acc[i][j] = __builtin_amdgcn_mfma_f32_16x16x32_bf16(av[i], bv[j], acc[i][j], 0, 0, 0);
    }
    __syncthreads();                            // protect LDS before next stage
  }

  // epilogue: D col = lane&15, row = (lane>>4)*4 + r   [verified mapping]
  const int colb = tn * 128 + n0 + (l & 15);
  const int rowb = tm * 128 + m0 + ((l >> 4) << 2);
#pragma unroll
  for (int j = 0; j < 4; ++j) {
    const int col = colb + j * 16;
    const float bv = (EPI == 2) ? 0.f : bias[col];
#pragma unroll
    for (int i = 0; i < 4; ++i)
#pragma unroll
      for (int r = 0; r < 4; ++r) {
        const int row = rowb + i * 16 + r;
        float xv = acc[i][j][r] + bv;
        if (EPI == 0) xv = tanhfast(xv);
        C[(size_t)row * 256 + col] = f2bf(xv);
      }
  }
}

// ---------------- scan helpers ----------------
template <int ITER>
__device__ __forceinline__ void compute_Ab(float zf, float ag, float hp, float dr, bool isT0,
                                           float& Aa, float& bb) {
  const float u = sigm(ag);
  if (isT0) {
    Aa = 0.f; bb = (1.f - u) * zf;
  } else {
    const float g = u * (1.f - u) * dr;
    Aa = u + (hp - zf) * g;
    bb = u * hp + (1.f - u) * zf - Aa * hp;
  }
}

// pass 1: per-chunk (P = prod A, q = affine-combined b)
template <int ITER>
__global__ __launch_bounds__(256) void scan_p1_kernel(
    const u16* __restrict__ zb, const u16* __restrict__ zub,
    const u16* __restrict__ s1b, const u16* __restrict__ hw0, const u16* __restrict__ hw1,
    const float* __restrict__ Wf_rec, const float* __restrict__ Wb_rec,
    float* __restrict__ P, float* __restrict__ q) {
  const int wid = blockIdx.x * 4 + (threadIdx.x >> 6);
  const int lane = threadIdx.x & 63;
  const int c = wid & 63;
  int tmp = wid >> 6;
  const int hb = tmp & 3; tmp >>= 2;
  const int b = tmp & 7;
  const int d = tmp >> 3;
  const int h = hb * 64 + lane;
  const float dr = (d ? Wb_rec : Wf_rec)[h * 257];
  const size_t off = ((size_t)b * T_ + (size_t)c * CHL) * H_ + h;
  const u16* zp = zb + (size_t)d * MH + off;
  const u16* zup = zub + (size_t)d * MH + off;
  const u16* s1p = s1b + (size_t)d * MH + off;
  const u16* hwp = (d ? hw1 : hw0) + off;
  const bool chunk0 = (c == 0);
  float Pv = 1.f, qv = 0.f;
#pragma unroll 4
  for (int it = 0; it < CHL; ++it) {
    const size_t ix = (size_t)it * H_;
    float zf = bf2f(zp[ix]);
    float ag = bf2f(zup[ix]);
    float hp = 0.f;
    if (ITER == 2) { ag += bf2f(hwp[ix]); hp = bf2f(s1p[ix]); }
    float Aa, bb;
    compute_Ab<ITER>(zf, ag, hp, dr, chunk0 && it == 0, Aa, bb);
    qv = Aa * qv + bb;
    Pv *= Aa;
  }
  const int ch = (d * 8 + b) * 256 + h;
  P[c * NCHAN + ch] = Pv;
  q[c * NCHAN + ch] = qv;
}

// pass 2: exclusive scan over chunk summaries per channel
__global__ __launch_bounds__(256) void scan_p2_kernel(const float* __restrict__ P,
                                                      const float* __restrict__ q,
                                                      float* __restrict__ hstart) {
  const int ch = blockIdx.x * 256 + threadIdx.x;    // 0..4095
  float hs = 0.f;
#pragma unroll 8
  for (int c = 0; c < NCH; ++c) {
    hstart[c * NCHAN + ch] = hs;
    hs = P[c * NCHAN + ch] * hs + q[c * NCHAN + ch];
  }
}

// pass 3: replay chunk with known h_start, emit states
template <int ITER>
__global__ __launch_bounds__(256) void scan_p3_kernel(
    const u16* __restrict__ zb, const u16* __restrict__ zub,
    const u16* __restrict__ s1b, const u16* __restrict__ hw0, const u16* __restrict__ hw1,
    const float* __restrict__ Wf_rec, const float* __restrict__ Wb_rec,
    const float* __restrict__ hstart,
    u16* __restrict__ s1out, float* __restrict__ out, float* __restrict__ hn) {
  const int wid = blockIdx.x * 4 + (threadIdx.x >> 6);
  const int lane = threadIdx.x & 63;
  const int c = wid & 63;
  int tmp = wid >> 6;
  const int hb = tmp & 3; tmp >>= 2;
  const int b = tmp & 7;
  const int d = tmp >> 3;
  const int h = hb * 64 + lane;
  const float dr = (d ? Wb_rec : Wf_rec)[h * 257];
  const size_t off = ((size_t)b * T_ + (size_t)c * CHL) * H_ + h;
  const u16* zp = zb + (size_t)d * MH + off;
  const u16* zup = zub + (size_t)d * MH + off;
  const u16* s1p = s1b + (size_t)d * MH + off;
  const u16* hwp = (d ? hw1 : hw0) + off;
  const int ch = (d * 8 + b) * 256 + h;
  float hcur = hstart[c * NCHAN + ch];
  if (ITER == 1 && c == 0) {
    // s1 holds states1 shifted by +1 row; row t=0 is h_{-1} = 0
    s1out[(size_t)d * MH + (size_t)b * T_ * H_ + h] = 0;
  }
  const bool chunk0 = (c == 0);
#pragma unroll 4
  for (int it = 0; it < CHL; ++it) {
    const size_t ix = (size_t)it * H_;
    float zf = bf2f(zp[ix]);
    float ag = bf2f(zup[ix]);
    float hp = 0.f;
    if (ITER == 2) { ag += bf2f(hwp[ix]); hp = bf2f(s1p[ix]); }
    float Aa, bb;
    compute_Ab<ITER>(zf, ag, hp, dr, chunk0 && it == 0, Aa, bb);
    hcur = Aa * hcur + bb;
    const int t = c * CHL + it;
    if (ITER == 1) {
      if (t < T_ - 1)
        s1out[(size_t)d * MH + ((size_t)b * T_ + t + 1) * H_ + h] = f2bf(hcur);
    } else {
      const size_t to = (d == 0) ? ((size_t)b * T_ + t) * 512 + h
                                 : ((size_t)b * T_ + (T_ - 1 - t)) * 512 + 256 + h;
      out[to] = hcur;
      if (t == T_ - 1) hn[(size_t)(d * 8 + b) * 256 + h] = hcur;
    }
  }
}

// ---------------- host ----------------
extern "C" void kernel_launch(void* const* d_in, const int* in_sizes, int n_in,
                              void* d_out, int out_size, void* d_ws, size_t ws_size,
                              hipStream_t stream) {
  const float* x      = (const float*)d_in[0];
  const float* Wf_in  = (const float*)d_in[1];
  const float* bf_in  = (const float*)d_in[2];
  const float* Wf_rec = (const float*)d_in[3];
  const float* Uf_z   = (const float*)d_in[4];
  const float* bf_u   = (const float*)d_in[5];
  const float* Wb_in  = (const float*)d_in[6];
  const float* bb_in  = (const float*)d_in[7];
  const float* Wb_rec = (const float*)d_in[8];
  const float* Ub_z   = (const float*)d_in[9];
  const float* bb_u   = (const float*)d_in[10];

  char* ws = (char*)d_ws;
  const size_t BF = 33554432;                   // bytes of one bf16 [M_ x H_] buffer
  u16* xf  = (u16*)(ws + 0 * BF);               // x as bf16; dead after GEMM1s
  u16* z0  = (u16*)(ws + 1 * BF);               // z fwd  (z0,z1 contiguous: [2][M][H])
  u16* z1  = (u16*)(ws + 2 * BF);
  u16* zu0 = (u16*)(ws + 3 * BF);
  u16* zu1 = (u16*)(ws + 4 * BF);
  u16* s10 = (u16*)(ws + 5 * BF);               // states1 shifted (+1 row), both dirs contiguous
  u16* s11 = (u16*)(ws + 6 * BF);
  u16* hw1 = (u16*)(ws + 7 * BF);
  u16* hw0 = xf;                                // alias: xf dead by the time GEMM3 runs
  float* Pbuf = (float*)(ws + 8 * BF);
  float* qbuf = (float*)(ws + 8 * BF + 1048576);
  float* hst  = (float*)(ws + 8 * BF + 2097152);
  u16* wbf    = (u16*)(ws + 8 * BF + 3145728);  // 6 x 256x256 bf16 weights
  (void)ws_size; (void)in_sizes; (void)n_in; (void)out_size;

  float* outp = (float*)d_out;                  // (B,T,512)
  float* hnp  = outp + (size_t)33554432;        // (2,B,256)

  dim3 gg(512, 2, 1);

  cvt_x_kernel<<<8192, 256, 0, stream>>>(x, xf);
  cvt_w_kernel<<<1536, 256, 0, stream>>>(Wf_in, Uf_z, Wf_rec, Wb_in, Ub_z, Wb_rec, wbf);

  // z = tanh(x W_in^T + b_in)   (bwd reads x time-reversed per batch)
  gemm_k<0, 0><<<gg, 256, 0, stream>>>(xf, wbf + 0 * 65536, bf_in, z0);
  gemm_k<0, 1><<<gg, 256, 0, stream>>>(xf, wbf + 3 * 65536, bb_in, z1);
  // zu = z U_z^T + b_u
  gemm_k<1, 0><<<gg, 256, 0, stream>>>(z0, wbf + 1 * 65536, bf_u, zu0);
  gemm_k<1, 0><<<gg, 256, 0, stream>>>(z1, wbf + 4 * 65536, bb_u, zu1);

  // DEER iteration 1 (h_prev = 0): chunked scan
  scan_p1_kernel<1><<<1024, 256, 0, stream>>>(z0, zu0, s10, hw0, hw1, Wf_rec, Wb_rec, Pbuf, qbuf);
  scan_p2_kernel<<<16, 256, 0, stream>>>(Pbuf, qbuf, hst);
  scan_p3_kernel<1><<<1024, 256, 0, stream>>>(z0, zu0, s10, hw0, hw1, Wf_rec, Wb_rec, hst,
                                              s10, nullptr, nullptr);

  // hw = states1_shifted W_rec^T
  gemm_k<2, 0><<<gg, 256, 0, stream>>>(s10, wbf + 2 * 65536, nullptr, hw0);
  gemm_k<2, 0><<<gg, 256, 0, stream>>>(s11, wbf + 5 * 65536, nullptr, hw1);

  // DEER iteration 2: chunked scan, write final output + h_n
  scan_p1_kernel<2><<<1024, 256, 0, stream>>>(z0, zu0, s10, hw0, hw1, Wf_rec, Wb_rec, Pbuf, qbuf);
  scan_p2_kernel<<<16, 256, 0, stream>>>(Pbuf, qbuf, hst);
  scan_p3_kernel<2><<<1024, 256, 0, stream>>>(z0, zu0, s10, hw0, hw1, Wf_rec, Wb_rec, hst,
                                              nullptr, outp, hnp);
}